// Round 9
// baseline (108.271 us; speedup 1.0000x reference)
//
#include <hip/hip_runtime.h>
#include <hip/hip_bf16.h>

#define NN 7936
#define EE 63488
#define CIN 5
#define WW 64
#define KK 8
#define H1C 64
#define H2C 16
#define T1 57            // 64-8+1
#define T2 50            // 57-8+1
#define FT (T1*H2C)      // 912 elems per node for xt (f16)
#define CAP 64           // fixed bucket capacity (P(deg>=64) ~ 1e-35)
#define GSTR 24          // gs row stride in halves (48 B: 16-B aligned rows)

typedef _Float16 half8 __attribute__((ext_vector_type(8)));
typedef _Float16 half4v __attribute__((ext_vector_type(4)));
typedef float f32x4 __attribute__((ext_vector_type(4)));

// ---------------------------------------------------------------------------
// Per-block int64-layout detection: first wave checks high words of the first
// 32 edge indices, ballot, LDS broadcast. ~32 L2-hot ints per block.
__device__ __forceinline__ int block_flag(const int* __restrict__ ei,
                                          int* sflag) {
    if (threadIdx.x < 64) {
        int bad = (threadIdx.x < 32) ? (ei[2 * threadIdx.x + 1] != 0) : 0;
        unsigned long long b = __ballot(bad);
        if (threadIdx.x == 0) *sflag = (b == 0ULL) ? 1 : 0;
    }
    __syncthreads();
    return *sflag;
}

__device__ __forceinline__ int load_row(const int* ei, int f, int e) {
    return f ? ei[2 * e] : ei[e];
}
__device__ __forceinline__ int load_col(const int* ei, int f, int e) {
    return f ? ei[2 * (EE + e)] : ei[EE + e];
}

// ---------------------------------------------------------------------------
// k_init: blocks 0..61 zero deg|cnt (contiguous 2*NN words, 62*256 = 15872
// exactly); blocks 62..161 do weight prep (25600 threads).
// w2p k-order: element e of a B-frag is (ci = g*4 + (e&3), tap = 2*s+(e>>2))
// — taps grouped in halves so the gc2 A-frag is a plain concat of two 8-B
// LDS rows. MFMA sums over k, so any A/B-consistent k-permutation is valid.
__global__ void k_init(float* __restrict__ deg,
                       const float* __restrict__ Wc2, _Float16* __restrict__ w2p,
                       const float* __restrict__ Wc1, _Float16* __restrict__ w1p,
                       const float* __restrict__ Wg, _Float16* __restrict__ wgp) {
    int b = blockIdx.x;
    if (b < 62) {
        // deg and cnt are contiguous in ws: zero both as one word range
        ((int*)deg)[b * 256 + threadIdx.x] = 0;
        return;
    }
    int i = (b - 62) * 256 + threadIdx.x;
    if (i < 16384) {
        // conv2 B-frags: slot=(s*4+lg)*128+nt*16+c, elem e
        int e = i & 7;
        int slot = i >> 3;
        int c  = slot & 15;
        int nt = (slot >> 4) & 7;
        int g  = (slot >> 7) & 3;
        int s  = (slot >> 9) & 3;
        int ci = g * 4 + (e & 3);
        w2p[i] = (_Float16)Wc2[(nt * 16 + c) * 128 + ci * 8 + 2 * s + (e >> 2)];
    } else if (i < 16384 + 8192) {
        // conv1 GEMM1 A-frags with sigma channel permutation
        int j = i - 16384;
        int e = j & 7;
        int m = (j >> 3) & 127;
        int slg = j >> 10;              // 0..7 = s*4+lg
        int ci = (slg >> 2) * 4 + (slg & 3);
        int hi = m >> 6;                // 0 = P, 1 = Q
        int mb = m & 63;
        int mt = mb >> 4, r = mb & 15;
        int sig = hi * 64 + 32 * (mt >> 1) + 8 * (r >> 2) + 4 * (mt & 1) + (r & 3);
        w1p[j] = (ci < CIN) ? (_Float16)Wc1[sig * (CIN * KK) + ci * KK + e]
                            : (_Float16)0.0f;
    } else if (i < 16384 + 8192 + 1024) {
        // conv1 GEMM2 B-frags (Wg)
        int j = i - 16384 - 8192;
        int e = j & 7;
        int f = (j >> 3) & 15;
        int slg = j >> 7;               // 0..7
        int c = (slg >> 2) * 32 + (slg & 3) * 8 + e;
        wgp[j] = (_Float16)Wg[c * H2C + f];
    }
}

// ---------------------------------------------------------------------------
// k_deg: single edge pass, ONE atomic per edge (the cnt atomic moved to the
// fill pass, which uses it as the bucket cursor).
__global__ void k_deg(const int* __restrict__ ei, const float* __restrict__ ew,
                      float* __restrict__ deg) {
    __shared__ int sflag;
    int f = block_flag(ei, &sflag);
    int e = blockIdx.x * 256 + threadIdx.x;
    int c = load_col(ei, f, e);
    atomicAdd(&deg[c], ew[e]);
}

// ---------------------------------------------------------------------------
// Merged kernel: blocks [0, NN/4) run conv1 (register-resident, wave = node);
// blocks [NN/4, NN/4+EE/256) run the edge bucket-fill into FIXED-CAPACITY
// buckets em[c*64+pos].
__global__ __launch_bounds__(256, 3) void k_conv1_fill(
        const float* __restrict__ x, const _Float16* __restrict__ w1p,
        const float* __restrict__ b1, const _Float16* __restrict__ wgp,
        _Float16* __restrict__ xt,
        const int* __restrict__ ei,
        const float* __restrict__ ew, const float* __restrict__ deg,
        int* __restrict__ cnt, int2* __restrict__ em) {
    if (blockIdx.x >= NN / 4) {
        // ---- bucket fill: em[c*64+pos] = (src, dinv[src]*ew) ----
        __shared__ int sflag;
        int f = block_flag(ei, &sflag);
        int e = (blockIdx.x - NN / 4) * 256 + threadIdx.x;
        if (e < EE) {
            int c = load_col(ei, f, e);
            int r = load_row(ei, f, e);
            int pos = atomicAdd(&cnt[c], 1);
            if (pos < CAP)
                em[(c << 6) + pos] =
                    make_int2(r, __float_as_int(rsqrtf(deg[r] + 1.0f) * ew[e]));
        }
        return;
    }
    // ---- conv1, fully register-resident (zero LDS, zero barriers) ----
    int tid = threadIdx.x;
    int w = tid >> 6, lane = tid & 63;
    int lc = lane & 15, lg = lane >> 4;
    int n = blockIdx.x * 4 + w;
    const float* xg = x + (size_t)n * (CIN * WW);

    const half8* w1v = (const half8*)w1p;
    const half8* wgv = (const half8*)wgp;

    half8 av[2][8];
#pragma unroll
    for (int s = 0; s < 2; ++s)
#pragma unroll
        for (int mt = 0; mt < 8; ++mt)
            av[s][mt] = w1v[(s * 4 + lg) * 128 + mt * 16 + lc];
    half8 bw[2];
#pragma unroll
    for (int s2 = 0; s2 < 2; ++s2) bw[s2] = wgv[(s2 * 4 + lg) * 16 + lc];

    const float* xr0 = xg + (size_t)lg * WW;
    const float* xr1 = xg + (size_t)(4 + lg) * WW;
    bool cok1 = (4 + lg) < CIN;

    f32x4 acc2[4];
#pragma unroll
    for (int mt2 = 0; mt2 < 4; ++mt2) acc2[mt2] = (f32x4)0.0f;

#pragma unroll
    for (int nt = 0; nt < 4; ++nt) {
        int t = nt * 16 + lc;
        half8 bf0, bf1;
#pragma unroll
        for (int e = 0; e < 8; ++e) {
            int tp = t + e;
            bf0[e] = (_Float16)((tp < WW) ? xr0[tp] : 0.0f);
            bf1[e] = (_Float16)((cok1 && tp < WW) ? xr1[tp] : 0.0f);
        }
        f32x4 acc[8];
#pragma unroll
        for (int mt = 0; mt < 8; ++mt) acc[mt] = (f32x4)0.0f;
#pragma unroll
        for (int mt = 0; mt < 8; ++mt)
            acc[mt] = __builtin_amdgcn_mfma_f32_16x16x32_f16(av[0][mt], bf0,
                                                             acc[mt], 0, 0, 0);
#pragma unroll
        for (int mt = 0; mt < 8; ++mt)
            acc[mt] = __builtin_amdgcn_mfma_f32_16x16x32_f16(av[1][mt], bf1,
                                                             acc[mt], 0, 0, 0);
        half4v h4[4];
#pragma unroll
        for (int mtp = 0; mtp < 4; ++mtp) {
            int cb = 32 * (mtp >> 1) + 8 * lg + 4 * (mtp & 1);
            float4 bP = *(const float4*)(b1 + cb);
            float4 bQ = *(const float4*)(b1 + 64 + cb);
            f32x4 P = acc[mtp];
            f32x4 Q = acc[mtp + 4];
            half4v hh;
            hh[0] = (_Float16)((P[0] + bP.x) * (1.0f / (1.0f + __expf(-(Q[0] + bQ.x)))));
            hh[1] = (_Float16)((P[1] + bP.y) * (1.0f / (1.0f + __expf(-(Q[1] + bQ.y)))));
            hh[2] = (_Float16)((P[2] + bP.z) * (1.0f / (1.0f + __expf(-(Q[2] + bQ.z)))));
            hh[3] = (_Float16)((P[3] + bP.w) * (1.0f / (1.0f + __expf(-(Q[3] + bQ.w)))));
            h4[mtp] = hh;
        }
#pragma unroll
        for (int s2 = 0; s2 < 2; ++s2) {
            half8 af = __builtin_shufflevector(h4[2 * s2], h4[2 * s2 + 1],
                                               0, 1, 2, 3, 4, 5, 6, 7);
            acc2[nt] = __builtin_amdgcn_mfma_f32_16x16x32_f16(af, bw[s2],
                                                              acc2[nt], 0, 0, 0);
        }
    }

    _Float16* xtn = xt + (size_t)n * FT;
#pragma unroll
    for (int mt2 = 0; mt2 < 4; ++mt2) {
#pragma unroll
        for (int j = 0; j < 4; ++j) {
            int t = mt2 * 16 + 4 * lg + j;
            if (t < T1) xtn[t * 16 + lc] = (_Float16)acc2[mt2][j];
        }
    }
}

// ---------------------------------------------------------------------------
// Fused gather + conv2, TWO WAVES PER NODE (retry of r3's mechanism without
// its failure mode — no shfl em-cache, no extra register state):
//   wave h=0 owns half8 idx 0..63  (t rows 0..31),
//   wave h=1 owns half8 idx 64..113 (t rows 32..56, lanes<50).
// Per edge per wave: ONE 16-B load + 16 VALU (was 2+32) and 2x the waves ->
// double the memory-level parallelism at identical register pressure. em
// loads are duplicated across the node's two waves (same address -> L1/L2
// broadcast; em is 4MB L2-hot). One __syncthreads joins the halves; each
// wave computes 2 of the 4 ntp output quadrants.
// gs2 is per-NODE [t][f] with 48-B rows (b128 writes, b64 frag reads, k-order
// matched by w2p prep). LDS 18368 B/block -> 8 blocks/CU (was 6).
// Epilogue stores: LDS-staged coalesced NONTEMPORAL (keeps write stream out
// of L2 so xt stays resident — proven r1 vs r2).
__global__ __launch_bounds__(256, 4) void k_gc2(
        const _Float16* __restrict__ xt, const float* __restrict__ deg,
        const int* __restrict__ cnt, const int2* __restrict__ em,
        const float* __restrict__ bg, const _Float16* __restrict__ w2p,
        const float* __restrict__ b2, float* __restrict__ out) {
    __shared__ __align__(16) _Float16 gs2[2][58 * GSTR];   // per node, 2784 B
    __shared__ __align__(16) float gout[4][16 * T2];       // per wave, 3200 B
    int tid = threadIdx.x;
    int w = tid >> 6, lane = tid & 63;
    int lc = lane & 15, lg = lane >> 4;
    int nb = w >> 1, h = w & 1;
    int n = blockIdx.x * 2 + nb;
    bool act = (h == 0) || (lane < 50);
    int idx = (h << 6) + lane;          // half8 index into a node row

    float dc = rsqrtf(deg[n] + 1.0f);
    float a[8];
    {
        const half8* xs = (const half8*)(xt + (size_t)n * FT);
        half8 u = (half8)(_Float16)0.0f;
        if (act) u = xs[idx];
        float sw = dc * dc;
#pragma unroll
        for (int j = 0; j < 8; ++j) a[j] = (float)u[j] * sw;
    }
    int beg = n << 6;
    int m = min(cnt[n], CAP);
    int2 rw0 = make_int2(0, 0), rw1 = make_int2(0, 0);
    half8 c0 = (half8)(_Float16)0.0f;
    if (m > 0) {
        rw0 = em[beg];
        const half8* xr = (const half8*)(xt + (size_t)rw0.x * FT);
        if (act) c0 = xr[idx];
    }
    if (m > 1) rw1 = em[beg + 1];
    for (int i = 0; i < m; ++i) {
        float wv = __int_as_float(rw0.y) * dc;
        half8 d0 = c0;
        int2 rwn = (i + 2 < m) ? em[beg + i + 2] : rw1;
        if (i + 1 < m) {
            const half8* xr = (const half8*)(xt + (size_t)rw1.x * FT);
            c0 = (half8)(_Float16)0.0f;
            if (act) c0 = xr[idx];
        }
        rw0 = rw1; rw1 = rwn;
#pragma unroll
        for (int j = 0; j < 8; ++j) a[j] += (float)d0[j] * wv;
    }

    // relu + bias -> gs2[nb][t][f] (48-B rows). Lane owns t = idx>>1,
    // f = (idx&1)*8 .. +8. One b128 write per active lane.
    {
        _Float16* g = gs2[nb];
        int f0 = (lane & 1) * 8;
        int t0 = idx >> 1;
        float4 bgA = *(const float4*)(bg + f0);
        float4 bgB = *(const float4*)(bg + f0 + 4);
        float bv[8] = {bgA.x, bgA.y, bgA.z, bgA.w, bgB.x, bgB.y, bgB.z, bgB.w};
        half8 h0;
#pragma unroll
        for (int j = 0; j < 8; ++j)
            h0[j] = (_Float16)fmaxf(a[j] + bv[j], 0.0f);
        if (act) *(half8*)(g + t0 * GSTR + f0) = h0;
    }
    __syncthreads();   // both halves' gs2 rows visible to both waves

    const _Float16* g = gs2[nb];
    half8 af[4][4];
#pragma unroll
    for (int s = 0; s < 4; ++s)
#pragma unroll
        for (int mt = 0; mt < 4; ++mt) {
            int tb = mt * 16 + lc + 2 * s;
            half4v lo = *(const half4v*)(g + tb * GSTR + lg * 4);
            half4v hh = *(const half4v*)(g + (tb + 1) * GSTR + lg * 4);
            af[s][mt] = __builtin_shufflevector(lo, hh, 0, 1, 2, 3, 4, 5, 6, 7);
        }

    const half8* wsv = (const half8*)w2p;
    float* outn = out + (size_t)n * (H1C * T2);
    float* go = gout[w];
#pragma unroll
    for (int np2 = 0; np2 < 2; ++np2) {
        int ntp = (h << 1) + np2;
        f32x4 aP[4], aQ[4];
#pragma unroll
        for (int mt = 0; mt < 4; ++mt) { aP[mt] = (f32x4)0.0f; aQ[mt] = (f32x4)0.0f; }
#pragma unroll
        for (int s = 0; s < 4; ++s) {
            half8 bP = wsv[(s * 4 + lg) * 128 + ntp * 16 + lc];
            half8 bQ = wsv[(s * 4 + lg) * 128 + (ntp + 4) * 16 + lc];
#pragma unroll
            for (int mt = 0; mt < 4; ++mt) {
                aP[mt] = __builtin_amdgcn_mfma_f32_16x16x32_f16(af[s][mt], bP,
                                                                aP[mt], 0, 0, 0);
                aQ[mt] = __builtin_amdgcn_mfma_f32_16x16x32_f16(af[s][mt], bQ,
                                                                aQ[mt], 0, 0, 0);
            }
        }
        int c = ntp * 16 + lc;
        float bp = b2[c], bq = b2[64 + c];
        // stage [lc][t<50] into wave-private LDS (column-major rows of 50)
#pragma unroll
        for (int mt = 0; mt < 4; ++mt) {
#pragma unroll
            for (int e2 = 0; e2 < 4; ++e2) {
                int t = mt * 16 + lg * 4 + e2;
                if (t < T2) {
                    float vv = (aP[mt][e2] + bp) *
                               (1.0f / (1.0f + __expf(-(aQ[mt][e2] + bq))));
                    go[lc * T2 + t] = vv;
                }
            }
        }
        // coalesced nontemporal writeback: 800 floats = 3x1024B + 128B
        float* dst = outn + ntp * (16 * T2);
#pragma unroll
        for (int i = 0; i < 3; ++i) {
            f32x4 v = *(const f32x4*)(go + i * 256 + lane * 4);
            __builtin_nontemporal_store(v, (f32x4*)(dst + i * 256 + lane * 4));
        }
        if (lane < 8) {
            f32x4 v = *(const f32x4*)(go + 768 + lane * 4);
            __builtin_nontemporal_store(v, (f32x4*)(dst + 768 + lane * 4));
        }
    }
}

// ---------------------------------------------------------------------------
extern "C" void kernel_launch(void* const* d_in, const int* in_sizes, int n_in,
                              void* d_out, int out_size, void* d_ws, size_t ws_size,
                              hipStream_t stream) {
    const float* x   = (const float*)d_in[0];
    const int*   ei  = (const int*)d_in[1];
    const float* ea  = (const float*)d_in[2];
    const float* Wc1 = (const float*)d_in[4];
    const float* b1  = (const float*)d_in[5];
    const float* Wg  = (const float*)d_in[6];
    const float* bg  = (const float*)d_in[7];
    const float* Wc2 = (const float*)d_in[8];
    const float* b2  = (const float*)d_in[9];
    float* out = (float*)d_out;

    char* ws = (char*)d_ws;
    size_t off = 0;
    auto alloc = [&](size_t bytes) -> void* {
        void* p = ws + off;
        off += (bytes + 255) & ~(size_t)255;
        return p;
    };
    // deg | cnt contiguous -> k_init zeroes both as one 2*NN word range
    float*    deg = (float*)alloc((size_t)NN * 4);      // 31744
    int*      cnt = (int*)alloc((size_t)NN * 4);        // 31744
    int2*     em  = (int2*)alloc((size_t)NN * CAP * 8); // 4.06 MB fixed-cap
    _Float16* xt  = (_Float16*)alloc((size_t)NN * FT * 2);
    _Float16* w2p = (_Float16*)alloc((size_t)16384 * 2);
    _Float16* w1p = (_Float16*)alloc((size_t)8192 * 2);
    _Float16* wgp = (_Float16*)alloc((size_t)1024 * 2);
    (void)ws_size; (void)in_sizes; (void)n_in; (void)out_size;

    k_init<<<162, 256, 0, stream>>>(deg, Wc2, w2p, Wc1, w1p, Wg, wgp);
    k_deg<<<EE / 256, 256, 0, stream>>>(ei, ea, deg);
    k_conv1_fill<<<NN / 4 + EE / 256, 256, 0, stream>>>(x, w1p, b1, wgp, xt,
                                                        ei, ea, deg, cnt, em);
    k_gc2<<<NN / 2, 256, 0, stream>>>(xt, deg, cnt, em, bg, w2p, b2, out);
}

// Round 10
// 104.114 us; speedup vs baseline: 1.0399x; 1.0399x over previous
//
#include <hip/hip_runtime.h>
#include <hip/hip_bf16.h>

#define NN 7936
#define EE 63488
#define CIN 5
#define WW 64
#define KK 8
#define H1C 64
#define H2C 16
#define T1 57            // 64-8+1
#define T2 50            // 57-8+1
#define FT (T1*H2C)      // 912 elems per node for xt (f16)
#define CAP 64           // fixed bucket capacity (P(deg>=64) ~ 1e-35)
#define GSTR 24          // gs row stride in halves (48 B: 16-B aligned rows)

typedef _Float16 half8 __attribute__((ext_vector_type(8)));
typedef _Float16 half4v __attribute__((ext_vector_type(4)));
typedef float f32x4 __attribute__((ext_vector_type(4)));

// ---------------------------------------------------------------------------
// Per-block int64-layout detection: first wave checks high words of the first
// 32 edge indices, ballot, LDS broadcast. ~32 L2-hot ints per block.
__device__ __forceinline__ int block_flag(const int* __restrict__ ei,
                                          int* sflag) {
    if (threadIdx.x < 64) {
        int bad = (threadIdx.x < 32) ? (ei[2 * threadIdx.x + 1] != 0) : 0;
        unsigned long long b = __ballot(bad);
        if (threadIdx.x == 0) *sflag = (b == 0ULL) ? 1 : 0;
    }
    __syncthreads();
    return *sflag;
}

__device__ __forceinline__ int load_row(const int* ei, int f, int e) {
    return f ? ei[2 * e] : ei[e];
}
__device__ __forceinline__ int load_col(const int* ei, int f, int e) {
    return f ? ei[2 * (EE + e)] : ei[EE + e];
}

// ---------------------------------------------------------------------------
// k_init: blocks 0..61 zero deg|cnt (contiguous 2*NN words, 62*256 = 15872
// exactly); blocks 62..161 do weight prep (25600 threads).
// w2p k-order: element e of a B-frag is (ci = g*4 + (e&3), tap = 2*s+(e>>2))
// — taps grouped in halves so the gc2 A-frag is a plain concat of two 8-B
// LDS rows. MFMA sums over k, so any A/B-consistent k-permutation is valid.
__global__ void k_init(float* __restrict__ deg,
                       const float* __restrict__ Wc2, _Float16* __restrict__ w2p,
                       const float* __restrict__ Wc1, _Float16* __restrict__ w1p,
                       const float* __restrict__ Wg, _Float16* __restrict__ wgp) {
    int b = blockIdx.x;
    if (b < 62) {
        // deg and cnt are contiguous in ws: zero both as one word range
        ((int*)deg)[b * 256 + threadIdx.x] = 0;
        return;
    }
    int i = (b - 62) * 256 + threadIdx.x;
    if (i < 16384) {
        // conv2 B-frags: slot=(s*4+lg)*128+nt*16+c, elem e
        int e = i & 7;
        int slot = i >> 3;
        int c  = slot & 15;
        int nt = (slot >> 4) & 7;
        int g  = (slot >> 7) & 3;
        int s  = (slot >> 9) & 3;
        int ci = g * 4 + (e & 3);
        w2p[i] = (_Float16)Wc2[(nt * 16 + c) * 128 + ci * 8 + 2 * s + (e >> 2)];
    } else if (i < 16384 + 8192) {
        // conv1 GEMM1 A-frags with sigma channel permutation
        int j = i - 16384;
        int e = j & 7;
        int m = (j >> 3) & 127;
        int slg = j >> 10;              // 0..7 = s*4+lg
        int ci = (slg >> 2) * 4 + (slg & 3);
        int hi = m >> 6;                // 0 = P, 1 = Q
        int mb = m & 63;
        int mt = mb >> 4, r = mb & 15;
        int sig = hi * 64 + 32 * (mt >> 1) + 8 * (r >> 2) + 4 * (mt & 1) + (r & 3);
        w1p[j] = (ci < CIN) ? (_Float16)Wc1[sig * (CIN * KK) + ci * KK + e]
                            : (_Float16)0.0f;
    } else if (i < 16384 + 8192 + 1024) {
        // conv1 GEMM2 B-frags (Wg)
        int j = i - 16384 - 8192;
        int e = j & 7;
        int f = (j >> 3) & 15;
        int slg = j >> 7;               // 0..7
        int c = (slg >> 2) * 32 + (slg & 3) * 8 + e;
        wgp[j] = (_Float16)Wg[c * H2C + f];
    }
}

// ---------------------------------------------------------------------------
// Merged kernel: blocks [0, NN/4) run conv1 (register-resident, wave = node);
// blocks [NN/4, NN/4+EE/256) run the edge bucket-fill into FIXED-CAPACITY
// buckets em[c*64+pos], storing RAW (src, ew) and accumulating deg[c] here
// (the dinv[src] fold moved into gc2's prefetch path — this deletes the
// separate k_deg edge pass and its launch).
__global__ __launch_bounds__(256, 3) void k_conv1_fill(
        const float* __restrict__ x, const _Float16* __restrict__ w1p,
        const float* __restrict__ b1, const _Float16* __restrict__ wgp,
        _Float16* __restrict__ xt,
        const int* __restrict__ ei,
        const float* __restrict__ ew, float* __restrict__ deg,
        int* __restrict__ cnt, int2* __restrict__ em) {
    if (blockIdx.x >= NN / 4) {
        // ---- bucket fill: em[c*64+pos] = (src, ew); deg[c] += ew ----
        __shared__ int sflag;
        int f = block_flag(ei, &sflag);
        int e = (blockIdx.x - NN / 4) * 256 + threadIdx.x;
        if (e < EE) {
            int c = load_col(ei, f, e);
            int r = load_row(ei, f, e);
            float wv = ew[e];
            int pos = atomicAdd(&cnt[c], 1);
            atomicAdd(&deg[c], wv);
            if (pos < CAP)
                em[(c << 6) + pos] = make_int2(r, __float_as_int(wv));
        }
        return;
    }
    // ---- conv1, fully register-resident (zero LDS, zero barriers) ----
    int tid = threadIdx.x;
    int w = tid >> 6, lane = tid & 63;
    int lc = lane & 15, lg = lane >> 4;
    int n = blockIdx.x * 4 + w;
    const float* xg = x + (size_t)n * (CIN * WW);

    const half8* w1v = (const half8*)w1p;
    const half8* wgv = (const half8*)wgp;

    half8 av[2][8];
#pragma unroll
    for (int s = 0; s < 2; ++s)
#pragma unroll
        for (int mt = 0; mt < 8; ++mt)
            av[s][mt] = w1v[(s * 4 + lg) * 128 + mt * 16 + lc];
    half8 bw[2];
#pragma unroll
    for (int s2 = 0; s2 < 2; ++s2) bw[s2] = wgv[(s2 * 4 + lg) * 16 + lc];

    const float* xr0 = xg + (size_t)lg * WW;
    const float* xr1 = xg + (size_t)(4 + lg) * WW;
    bool cok1 = (4 + lg) < CIN;

    f32x4 acc2[4];
#pragma unroll
    for (int mt2 = 0; mt2 < 4; ++mt2) acc2[mt2] = (f32x4)0.0f;

#pragma unroll
    for (int nt = 0; nt < 4; ++nt) {
        int t = nt * 16 + lc;
        half8 bf0, bf1;
#pragma unroll
        for (int e = 0; e < 8; ++e) {
            int tp = t + e;
            bf0[e] = (_Float16)((tp < WW) ? xr0[tp] : 0.0f);
            bf1[e] = (_Float16)((cok1 && tp < WW) ? xr1[tp] : 0.0f);
        }
        f32x4 acc[8];
#pragma unroll
        for (int mt = 0; mt < 8; ++mt) acc[mt] = (f32x4)0.0f;
#pragma unroll
        for (int mt = 0; mt < 8; ++mt)
            acc[mt] = __builtin_amdgcn_mfma_f32_16x16x32_f16(av[0][mt], bf0,
                                                             acc[mt], 0, 0, 0);
#pragma unroll
        for (int mt = 0; mt < 8; ++mt)
            acc[mt] = __builtin_amdgcn_mfma_f32_16x16x32_f16(av[1][mt], bf1,
                                                             acc[mt], 0, 0, 0);
        half4v h4[4];
#pragma unroll
        for (int mtp = 0; mtp < 4; ++mtp) {
            int cb = 32 * (mtp >> 1) + 8 * lg + 4 * (mtp & 1);
            float4 bP = *(const float4*)(b1 + cb);
            float4 bQ = *(const float4*)(b1 + 64 + cb);
            f32x4 P = acc[mtp];
            f32x4 Q = acc[mtp + 4];
            half4v hh;
            hh[0] = (_Float16)((P[0] + bP.x) * (1.0f / (1.0f + __expf(-(Q[0] + bQ.x)))));
            hh[1] = (_Float16)((P[1] + bP.y) * (1.0f / (1.0f + __expf(-(Q[1] + bQ.y)))));
            hh[2] = (_Float16)((P[2] + bP.z) * (1.0f / (1.0f + __expf(-(Q[2] + bQ.z)))));
            hh[3] = (_Float16)((P[3] + bP.w) * (1.0f / (1.0f + __expf(-(Q[3] + bQ.w)))));
            h4[mtp] = hh;
        }
#pragma unroll
        for (int s2 = 0; s2 < 2; ++s2) {
            half8 af = __builtin_shufflevector(h4[2 * s2], h4[2 * s2 + 1],
                                               0, 1, 2, 3, 4, 5, 6, 7);
            acc2[nt] = __builtin_amdgcn_mfma_f32_16x16x32_f16(af, bw[s2],
                                                              acc2[nt], 0, 0, 0);
        }
    }

    _Float16* xtn = xt + (size_t)n * FT;
#pragma unroll
    for (int mt2 = 0; mt2 < 4; ++mt2) {
#pragma unroll
        for (int j = 0; j < 4; ++j) {
            int t = mt2 * 16 + 4 * lg + j;
            if (t < T1) xtn[t * 16 + lc] = (_Float16)acc2[mt2][j];
        }
    }
}

// ---------------------------------------------------------------------------
// Fused gather + conv2, TWO WAVES PER NODE (proven r9: warm 69µs, WRITE
// amplification eliminated):
//   wave h=0 owns half8 idx 0..63  (t rows 0..31),
//   wave h=1 owns half8 idx 64..113 (t rows 32..56, lanes<50).
// em now stores RAW (src, ew); dinv[src] is computed here in the PREFETCH
// path: deg[rw.x] is loaded 2 iterations ahead (wave-uniform, 32KB L2-hot)
// and wv = ew * rsqrt(deg[r]+1) happens off the critical chain. dc factors
// out of the loop entirely (one multiply after the gather).
// gs2 per-NODE [t][f] 48-B rows (b128 writes, b64 frag reads, k-order in
// w2p). One __syncthreads joins halves; each wave does 2 of 4 ntp quadrants.
// Epilogue stores: LDS-staged coalesced NONTEMPORAL (keeps write stream out
// of L2 so xt stays resident — proven r1 vs r2).
__global__ __launch_bounds__(256, 4) void k_gc2(
        const _Float16* __restrict__ xt, const float* __restrict__ deg,
        const int* __restrict__ cnt, const int2* __restrict__ em,
        const float* __restrict__ bg, const _Float16* __restrict__ w2p,
        const float* __restrict__ b2, float* __restrict__ out) {
    __shared__ __align__(16) _Float16 gs2[2][58 * GSTR];   // per node, 2784 B
    __shared__ __align__(16) float gout[4][16 * T2];       // per wave, 3200 B
    int tid = threadIdx.x;
    int w = tid >> 6, lane = tid & 63;
    int lc = lane & 15, lg = lane >> 4;
    int nb = w >> 1, h = w & 1;
    int n = blockIdx.x * 2 + nb;
    bool act = (h == 0) || (lane < 50);
    int idx = (h << 6) + lane;          // half8 index into a node row

    float dc = rsqrtf(deg[n] + 1.0f);
    float a[8];
    {
        const half8* xs = (const half8*)(xt + (size_t)n * FT);
        half8 u = (half8)(_Float16)0.0f;
        if (act) u = xs[idx];
#pragma unroll
        for (int j = 0; j < 8; ++j) a[j] = (float)u[j] * dc;   // self: x*dc
    }
    int beg = n << 6;
    int m = min(cnt[n], CAP);
    int2 rw0 = make_int2(0, 0), rw1 = make_int2(0, 0);
    float dg0 = 0.0f, dg1 = 0.0f;
    half8 c0 = (half8)(_Float16)0.0f;
    if (m > 0) {
        rw0 = em[beg];
        dg0 = deg[rw0.x];
        const half8* xr = (const half8*)(xt + (size_t)rw0.x * FT);
        if (act) c0 = xr[idx];
    }
    if (m > 1) { rw1 = em[beg + 1]; dg1 = deg[rw1.x]; }
    for (int i = 0; i < m; ++i) {
        float wv = __int_as_float(rw0.y) * rsqrtf(dg0 + 1.0f);
        half8 d0 = c0;
        int2 rwn = rw1;
        float dgn = dg1;
        if (i + 2 < m) { rwn = em[beg + i + 2]; dgn = deg[rwn.x]; }
        if (i + 1 < m) {
            const half8* xr = (const half8*)(xt + (size_t)rw1.x * FT);
            c0 = (half8)(_Float16)0.0f;
            if (act) c0 = xr[idx];
        }
        rw0 = rw1; dg0 = dg1; rw1 = rwn; dg1 = dgn;
#pragma unroll
        for (int j = 0; j < 8; ++j) a[j] += (float)d0[j] * wv;
    }

    // relu + bias -> gs2[nb][t][f] (48-B rows). Lane owns t = idx>>1,
    // f = (idx&1)*8 .. +8. One b128 write per active lane.
    // Final feature = dc * (x*dc + sum) + bg, relu.
    {
        _Float16* g = gs2[nb];
        int f0 = (lane & 1) * 8;
        int t0 = idx >> 1;
        float4 bgA = *(const float4*)(bg + f0);
        float4 bgB = *(const float4*)(bg + f0 + 4);
        float bv[8] = {bgA.x, bgA.y, bgA.z, bgA.w, bgB.x, bgB.y, bgB.z, bgB.w};
        half8 h0;
#pragma unroll
        for (int j = 0; j < 8; ++j)
            h0[j] = (_Float16)fmaxf(a[j] * dc + bv[j], 0.0f);
        if (act) *(half8*)(g + t0 * GSTR + f0) = h0;
    }
    __syncthreads();   // both halves' gs2 rows visible to both waves

    const _Float16* g = gs2[nb];
    half8 af[4][4];
#pragma unroll
    for (int s = 0; s < 4; ++s)
#pragma unroll
        for (int mt = 0; mt < 4; ++mt) {
            int tb = mt * 16 + lc + 2 * s;
            half4v lo = *(const half4v*)(g + tb * GSTR + lg * 4);
            half4v hh = *(const half4v*)(g + (tb + 1) * GSTR + lg * 4);
            af[s][mt] = __builtin_shufflevector(lo, hh, 0, 1, 2, 3, 4, 5, 6, 7);
        }

    const half8* wsv = (const half8*)w2p;
    float* outn = out + (size_t)n * (H1C * T2);
    float* go = gout[w];
#pragma unroll
    for (int np2 = 0; np2 < 2; ++np2) {
        int ntp = (h << 1) + np2;
        f32x4 aP[4], aQ[4];
#pragma unroll
        for (int mt = 0; mt < 4; ++mt) { aP[mt] = (f32x4)0.0f; aQ[mt] = (f32x4)0.0f; }
#pragma unroll
        for (int s = 0; s < 4; ++s) {
            half8 bP = wsv[(s * 4 + lg) * 128 + ntp * 16 + lc];
            half8 bQ = wsv[(s * 4 + lg) * 128 + (ntp + 4) * 16 + lc];
#pragma unroll
            for (int mt = 0; mt < 4; ++mt) {
                aP[mt] = __builtin_amdgcn_mfma_f32_16x16x32_f16(af[s][mt], bP,
                                                                aP[mt], 0, 0, 0);
                aQ[mt] = __builtin_amdgcn_mfma_f32_16x16x32_f16(af[s][mt], bQ,
                                                                aQ[mt], 0, 0, 0);
            }
        }
        int c = ntp * 16 + lc;
        float bp = b2[c], bq = b2[64 + c];
        // stage [lc][t<50] into wave-private LDS (column-major rows of 50)
#pragma unroll
        for (int mt = 0; mt < 4; ++mt) {
#pragma unroll
            for (int e2 = 0; e2 < 4; ++e2) {
                int t = mt * 16 + lg * 4 + e2;
                if (t < T2) {
                    float vv = (aP[mt][e2] + bp) *
                               (1.0f / (1.0f + __expf(-(aQ[mt][e2] + bq))));
                    go[lc * T2 + t] = vv;
                }
            }
        }
        // coalesced nontemporal writeback: 800 floats = 3x1024B + 128B
        float* dst = outn + ntp * (16 * T2);
#pragma unroll
        for (int i = 0; i < 3; ++i) {
            f32x4 v = *(const f32x4*)(go + i * 256 + lane * 4);
            __builtin_nontemporal_store(v, (f32x4*)(dst + i * 256 + lane * 4));
        }
        if (lane < 8) {
            f32x4 v = *(const f32x4*)(go + 768 + lane * 4);
            __builtin_nontemporal_store(v, (f32x4*)(dst + 768 + lane * 4));
        }
    }
}

// ---------------------------------------------------------------------------
extern "C" void kernel_launch(void* const* d_in, const int* in_sizes, int n_in,
                              void* d_out, int out_size, void* d_ws, size_t ws_size,
                              hipStream_t stream) {
    const float* x   = (const float*)d_in[0];
    const int*   ei  = (const int*)d_in[1];
    const float* ea  = (const float*)d_in[2];
    const float* Wc1 = (const float*)d_in[4];
    const float* b1  = (const float*)d_in[5];
    const float* Wg  = (const float*)d_in[6];
    const float* bg  = (const float*)d_in[7];
    const float* Wc2 = (const float*)d_in[8];
    const float* b2  = (const float*)d_in[9];
    float* out = (float*)d_out;

    char* ws = (char*)d_ws;
    size_t off = 0;
    auto alloc = [&](size_t bytes) -> void* {
        void* p = ws + off;
        off += (bytes + 255) & ~(size_t)255;
        return p;
    };
    // deg | cnt contiguous -> k_init zeroes both as one 2*NN word range
    float*    deg = (float*)alloc((size_t)NN * 4);      // 31744
    int*      cnt = (int*)alloc((size_t)NN * 4);        // 31744
    int2*     em  = (int2*)alloc((size_t)NN * CAP * 8); // 4.06 MB fixed-cap
    _Float16* xt  = (_Float16*)alloc((size_t)NN * FT * 2);
    _Float16* w2p = (_Float16*)alloc((size_t)16384 * 2);
    _Float16* w1p = (_Float16*)alloc((size_t)8192 * 2);
    _Float16* wgp = (_Float16*)alloc((size_t)1024 * 2);
    (void)ws_size; (void)in_sizes; (void)n_in; (void)out_size;

    k_init<<<162, 256, 0, stream>>>(deg, Wc2, w2p, Wc1, w1p, Wg, wgp);
    k_conv1_fill<<<NN / 4 + EE / 256, 256, 0, stream>>>(x, w1p, b1, wgp, xt,
                                                        ei, ea, deg, cnt, em);
    k_gc2<<<NN / 2, 256, 0, stream>>>(xt, deg, cnt, em, bg, w2p, b2, out);
}

// Round 11
// 102.695 us; speedup vs baseline: 1.0543x; 1.0138x over previous
//
#include <hip/hip_runtime.h>
#include <hip/hip_bf16.h>

#define NN 7936
#define EE 63488
#define CIN 5
#define WW 64
#define KK 8
#define H1C 64
#define H2C 16
#define T1 57            // 64-8+1
#define T2 50            // 57-8+1
#define FT (T1*H2C)      // 912 elems per node for xt (f16)
#define CAP 64           // fixed bucket capacity (P(deg>=64) ~ 1e-35)
#define GSTR 24          // gs row stride in halves (48 B: 16-B aligned rows)

typedef _Float16 half8 __attribute__((ext_vector_type(8)));
typedef _Float16 half4v __attribute__((ext_vector_type(4)));
typedef float f32x4 __attribute__((ext_vector_type(4)));

// ---------------------------------------------------------------------------
// Per-block int64-layout detection: first wave checks high words of the first
// 32 edge indices, ballot, LDS broadcast. ~32 L2-hot ints per block.
__device__ __forceinline__ int block_flag(const int* __restrict__ ei,
                                          int* sflag) {
    if (threadIdx.x < 64) {
        int bad = (threadIdx.x < 32) ? (ei[2 * threadIdx.x + 1] != 0) : 0;
        unsigned long long b = __ballot(bad);
        if (threadIdx.x == 0) *sflag = (b == 0ULL) ? 1 : 0;
    }
    __syncthreads();
    return *sflag;
}

__device__ __forceinline__ int load_row(const int* ei, int f, int e) {
    return f ? ei[2 * e] : ei[e];
}
__device__ __forceinline__ int load_col(const int* ei, int f, int e) {
    return f ? ei[2 * (EE + e)] : ei[EE + e];
}

// ---------------------------------------------------------------------------
// k_init: blocks 0..61 zero deg|cnt (contiguous 2*NN words, 62*256 = 15872
// exactly); blocks 62..161 do weight prep (25600 threads).
// w2p k-order: element e of a B-frag is (ci = g*4 + (e&3), tap = 2*s+(e>>2))
// — taps grouped in halves so the gc2 A-frag is a plain concat of two 8-B
// LDS rows. MFMA sums over k, so any A/B-consistent k-permutation is valid.
__global__ void k_init(float* __restrict__ deg,
                       const float* __restrict__ Wc2, _Float16* __restrict__ w2p,
                       const float* __restrict__ Wc1, _Float16* __restrict__ w1p,
                       const float* __restrict__ Wg, _Float16* __restrict__ wgp) {
    int b = blockIdx.x;
    if (b < 62) {
        // deg and cnt are contiguous in ws: zero both as one word range
        ((int*)deg)[b * 256 + threadIdx.x] = 0;
        return;
    }
    int i = (b - 62) * 256 + threadIdx.x;
    if (i < 16384) {
        // conv2 B-frags: slot=(s*4+lg)*128+nt*16+c, elem e
        int e = i & 7;
        int slot = i >> 3;
        int c  = slot & 15;
        int nt = (slot >> 4) & 7;
        int g  = (slot >> 7) & 3;
        int s  = (slot >> 9) & 3;
        int ci = g * 4 + (e & 3);
        w2p[i] = (_Float16)Wc2[(nt * 16 + c) * 128 + ci * 8 + 2 * s + (e >> 2)];
    } else if (i < 16384 + 8192) {
        // conv1 GEMM1 A-frags with sigma channel permutation
        int j = i - 16384;
        int e = j & 7;
        int m = (j >> 3) & 127;
        int slg = j >> 10;              // 0..7 = s*4+lg
        int ci = (slg >> 2) * 4 + (slg & 3);
        int hi = m >> 6;                // 0 = P, 1 = Q
        int mb = m & 63;
        int mt = mb >> 4, r = mb & 15;
        int sig = hi * 64 + 32 * (mt >> 1) + 8 * (r >> 2) + 4 * (mt & 1) + (r & 3);
        w1p[j] = (ci < CIN) ? (_Float16)Wc1[sig * (CIN * KK) + ci * KK + e]
                            : (_Float16)0.0f;
    } else if (i < 16384 + 8192 + 1024) {
        // conv1 GEMM2 B-frags (Wg)
        int j = i - 16384 - 8192;
        int e = j & 7;
        int f = (j >> 3) & 15;
        int slg = j >> 7;               // 0..7
        int c = (slg >> 2) * 32 + (slg & 3) * 8 + e;
        wgp[j] = (_Float16)Wg[c * H2C + f];
    }
}

// ---------------------------------------------------------------------------
// Merged kernel: blocks [0, NN/4) run conv1 (register-resident, wave = node);
// blocks [NN/4, NN/4+EE/256) run the edge bucket-fill into FIXED-CAPACITY
// buckets em[c*64+pos], storing RAW (src, ew) and accumulating deg[c] here
// (the dinv[src] fold lives in gc2's prefetch path).
__global__ __launch_bounds__(256, 3) void k_conv1_fill(
        const float* __restrict__ x, const _Float16* __restrict__ w1p,
        const float* __restrict__ b1, const _Float16* __restrict__ wgp,
        _Float16* __restrict__ xt,
        const int* __restrict__ ei,
        const float* __restrict__ ew, float* __restrict__ deg,
        int* __restrict__ cnt, int2* __restrict__ em) {
    if (blockIdx.x >= NN / 4) {
        // ---- bucket fill: em[c*64+pos] = (src, ew); deg[c] += ew ----
        __shared__ int sflag;
        int f = block_flag(ei, &sflag);
        int e = (blockIdx.x - NN / 4) * 256 + threadIdx.x;
        if (e < EE) {
            int c = load_col(ei, f, e);
            int r = load_row(ei, f, e);
            float wv = ew[e];
            int pos = atomicAdd(&cnt[c], 1);
            atomicAdd(&deg[c], wv);
            if (pos < CAP)
                em[(c << 6) + pos] = make_int2(r, __float_as_int(wv));
        }
        return;
    }
    // ---- conv1, fully register-resident (zero LDS, zero barriers) ----
    int tid = threadIdx.x;
    int w = tid >> 6, lane = tid & 63;
    int lc = lane & 15, lg = lane >> 4;
    int n = blockIdx.x * 4 + w;
    const float* xg = x + (size_t)n * (CIN * WW);

    const half8* w1v = (const half8*)w1p;
    const half8* wgv = (const half8*)wgp;

    half8 av[2][8];
#pragma unroll
    for (int s = 0; s < 2; ++s)
#pragma unroll
        for (int mt = 0; mt < 8; ++mt)
            av[s][mt] = w1v[(s * 4 + lg) * 128 + mt * 16 + lc];
    half8 bw[2];
#pragma unroll
    for (int s2 = 0; s2 < 2; ++s2) bw[s2] = wgv[(s2 * 4 + lg) * 16 + lc];

    const float* xr0 = xg + (size_t)lg * WW;
    const float* xr1 = xg + (size_t)(4 + lg) * WW;
    bool cok1 = (4 + lg) < CIN;

    f32x4 acc2[4];
#pragma unroll
    for (int mt2 = 0; mt2 < 4; ++mt2) acc2[mt2] = (f32x4)0.0f;

#pragma unroll
    for (int nt = 0; nt < 4; ++nt) {
        int t = nt * 16 + lc;
        half8 bf0, bf1;
#pragma unroll
        for (int e = 0; e < 8; ++e) {
            int tp = t + e;
            bf0[e] = (_Float16)((tp < WW) ? xr0[tp] : 0.0f);
            bf1[e] = (_Float16)((cok1 && tp < WW) ? xr1[tp] : 0.0f);
        }
        f32x4 acc[8];
#pragma unroll
        for (int mt = 0; mt < 8; ++mt) acc[mt] = (f32x4)0.0f;
#pragma unroll
        for (int mt = 0; mt < 8; ++mt)
            acc[mt] = __builtin_amdgcn_mfma_f32_16x16x32_f16(av[0][mt], bf0,
                                                             acc[mt], 0, 0, 0);
#pragma unroll
        for (int mt = 0; mt < 8; ++mt)
            acc[mt] = __builtin_amdgcn_mfma_f32_16x16x32_f16(av[1][mt], bf1,
                                                             acc[mt], 0, 0, 0);
        half4v h4[4];
#pragma unroll
        for (int mtp = 0; mtp < 4; ++mtp) {
            int cb = 32 * (mtp >> 1) + 8 * lg + 4 * (mtp & 1);
            float4 bP = *(const float4*)(b1 + cb);
            float4 bQ = *(const float4*)(b1 + 64 + cb);
            f32x4 P = acc[mtp];
            f32x4 Q = acc[mtp + 4];
            half4v hh;
            hh[0] = (_Float16)((P[0] + bP.x) * (1.0f / (1.0f + __expf(-(Q[0] + bQ.x)))));
            hh[1] = (_Float16)((P[1] + bP.y) * (1.0f / (1.0f + __expf(-(Q[1] + bQ.y)))));
            hh[2] = (_Float16)((P[2] + bP.z) * (1.0f / (1.0f + __expf(-(Q[2] + bQ.z)))));
            hh[3] = (_Float16)((P[3] + bP.w) * (1.0f / (1.0f + __expf(-(Q[3] + bQ.w)))));
            h4[mtp] = hh;
        }
#pragma unroll
        for (int s2 = 0; s2 < 2; ++s2) {
            half8 af = __builtin_shufflevector(h4[2 * s2], h4[2 * s2 + 1],
                                               0, 1, 2, 3, 4, 5, 6, 7);
            acc2[nt] = __builtin_amdgcn_mfma_f32_16x16x32_f16(af, bw[s2],
                                                              acc2[nt], 0, 0, 0);
        }
    }

    _Float16* xtn = xt + (size_t)n * FT;
#pragma unroll
    for (int mt2 = 0; mt2 < 4; ++mt2) {
#pragma unroll
        for (int j = 0; j < 4; ++j) {
            int t = mt2 * 16 + 4 * lg + j;
            if (t < T1) xtn[t * 16 + lc] = (_Float16)acc2[mt2][j];
        }
    }
}

// ---------------------------------------------------------------------------
// Fused gather + conv2, TWO WAVES PER NODE (r9/r10 proven: warm 65µs, write
// amplification eliminated).
// NEW this round: 2-DEEP row prefetch — row for edge i+2 is issued at
// iteration i (was 1-deep: issue at i-1, consume at i, wall ~= full miss
// latency). em/deg are prefetched 3-deep so the row address is always ready.
// Tail uses ZERO-WEIGHT SELF-ROW padding (valid address, wv = 0*rsqrt >= 0
// exact) -> no in-loop guards on the row path. Register cost: +1 half8 row
// slot, +1 em slot (~+8 VGPR) — far from the r4 spill regime (32 VGPR ring).
// gs2 per-NODE [t][f] 48-B rows; one __syncthreads; each wave does 2 of 4
// ntp quadrants; LDS-staged coalesced NONTEMPORAL stores.
__global__ __launch_bounds__(256, 4) void k_gc2(
        const _Float16* __restrict__ xt, const float* __restrict__ deg,
        const int* __restrict__ cnt, const int2* __restrict__ em,
        const float* __restrict__ bg, const _Float16* __restrict__ w2p,
        const float* __restrict__ b2, float* __restrict__ out) {
    __shared__ __align__(16) _Float16 gs2[2][58 * GSTR];   // per node, 2784 B
    __shared__ __align__(16) float gout[4][16 * T2];       // per wave, 3200 B
    int tid = threadIdx.x;
    int w = tid >> 6, lane = tid & 63;
    int lc = lane & 15, lg = lane >> 4;
    int nb = w >> 1, h = w & 1;
    int n = blockIdx.x * 2 + nb;
    bool act = (h == 0) || (lane < 50);
    int idx = (h << 6) + lane;          // half8 index into a node row

    float dc = rsqrtf(deg[n] + 1.0f);
    float a[8];
    {
        const half8* xs = (const half8*)(xt + (size_t)n * FT);
        half8 u = (half8)(_Float16)0.0f;
        if (act) u = xs[idx];
#pragma unroll
        for (int j = 0; j < 8; ++j) a[j] = (float)u[j] * dc;   // self: x*dc
    }
    int beg = n << 6;
    int m = min(cnt[n], CAP);

    // pad entries: self row (valid, L1-hot), weight bits = 0 -> wv exactly 0
#define LDEM(K) (((K) < m) ? em[beg + (K)] : make_int2(n, 0))
    int2 rw0 = LDEM(0), rw1 = LDEM(1), rw2 = LDEM(2);
    float dg0 = deg[rw0.x], dg1 = deg[rw1.x], dg2 = deg[rw2.x];
    half8 c0 = (half8)(_Float16)0.0f, c1 = (half8)(_Float16)0.0f;
    if (act) {
        c0 = ((const half8*)(xt + (size_t)rw0.x * FT))[idx];
        c1 = ((const half8*)(xt + (size_t)rw1.x * FT))[idx];
    }
    for (int i = 0; i < m; ++i) {
        float wv = __int_as_float(rw0.y) * rsqrtf(dg0 + 1.0f);
        half8 d = c0;
        // shift row ring; issue row for edge i+2 (address ready in rw2)
        c0 = c1;
        c1 = (half8)(_Float16)0.0f;
        if (act) c1 = ((const half8*)(xt + (size_t)rw2.x * FT))[idx];
        // prefetch em/deg for edge i+3
        int2 rwn = LDEM(i + 3);
        float dgn = deg[rwn.x];
        rw0 = rw1; dg0 = dg1;
        rw1 = rw2; dg1 = dg2;
        rw2 = rwn; dg2 = dgn;
#pragma unroll
        for (int j = 0; j < 8; ++j) a[j] += (float)d[j] * wv;
    }
#undef LDEM

    // relu + bias -> gs2[nb][t][f] (48-B rows). Lane owns t = idx>>1,
    // f = (idx&1)*8 .. +8. One b128 write per active lane.
    // Final feature = dc * (x*dc + sum) + bg, relu.
    {
        _Float16* g = gs2[nb];
        int f0 = (lane & 1) * 8;
        int t0 = idx >> 1;
        float4 bgA = *(const float4*)(bg + f0);
        float4 bgB = *(const float4*)(bg + f0 + 4);
        float bv[8] = {bgA.x, bgA.y, bgA.z, bgA.w, bgB.x, bgB.y, bgB.z, bgB.w};
        half8 h0;
#pragma unroll
        for (int j = 0; j < 8; ++j)
            h0[j] = (_Float16)fmaxf(a[j] * dc + bv[j], 0.0f);
        if (act) *(half8*)(g + t0 * GSTR + f0) = h0;
    }
    __syncthreads();   // both halves' gs2 rows visible to both waves

    const _Float16* g = gs2[nb];
    half8 af[4][4];
#pragma unroll
    for (int s = 0; s < 4; ++s)
#pragma unroll
        for (int mt = 0; mt < 4; ++mt) {
            int tb = mt * 16 + lc + 2 * s;
            half4v lo = *(const half4v*)(g + tb * GSTR + lg * 4);
            half4v hh = *(const half4v*)(g + (tb + 1) * GSTR + lg * 4);
            af[s][mt] = __builtin_shufflevector(lo, hh, 0, 1, 2, 3, 4, 5, 6, 7);
        }

    const half8* wsv = (const half8*)w2p;
    float* outn = out + (size_t)n * (H1C * T2);
    float* go = gout[w];
#pragma unroll
    for (int np2 = 0; np2 < 2; ++np2) {
        int ntp = (h << 1) + np2;
        f32x4 aP[4], aQ[4];
#pragma unroll
        for (int mt = 0; mt < 4; ++mt) { aP[mt] = (f32x4)0.0f; aQ[mt] = (f32x4)0.0f; }
#pragma unroll
        for (int s = 0; s < 4; ++s) {
            half8 bP = wsv[(s * 4 + lg) * 128 + ntp * 16 + lc];
            half8 bQ = wsv[(s * 4 + lg) * 128 + (ntp + 4) * 16 + lc];
#pragma unroll
            for (int mt = 0; mt < 4; ++mt) {
                aP[mt] = __builtin_amdgcn_mfma_f32_16x16x32_f16(af[s][mt], bP,
                                                                aP[mt], 0, 0, 0);
                aQ[mt] = __builtin_amdgcn_mfma_f32_16x16x32_f16(af[s][mt], bQ,
                                                                aQ[mt], 0, 0, 0);
            }
        }
        int c = ntp * 16 + lc;
        float bp = b2[c], bq = b2[64 + c];
        // stage [lc][t<50] into wave-private LDS (column-major rows of 50)
#pragma unroll
        for (int mt = 0; mt < 4; ++mt) {
#pragma unroll
            for (int e2 = 0; e2 < 4; ++e2) {
                int t = mt * 16 + lg * 4 + e2;
                if (t < T2) {
                    float vv = (aP[mt][e2] + bp) *
                               (1.0f / (1.0f + __expf(-(aQ[mt][e2] + bq))));
                    go[lc * T2 + t] = vv;
                }
            }
        }
        // coalesced nontemporal writeback: 800 floats = 3x1024B + 128B
        float* dst = outn + ntp * (16 * T2);
#pragma unroll
        for (int i = 0; i < 3; ++i) {
            f32x4 v = *(const f32x4*)(go + i * 256 + lane * 4);
            __builtin_nontemporal_store(v, (f32x4*)(dst + i * 256 + lane * 4));
        }
        if (lane < 8) {
            f32x4 v = *(const f32x4*)(go + 768 + lane * 4);
            __builtin_nontemporal_store(v, (f32x4*)(dst + 768 + lane * 4));
        }
    }
}

// ---------------------------------------------------------------------------
extern "C" void kernel_launch(void* const* d_in, const int* in_sizes, int n_in,
                              void* d_out, int out_size, void* d_ws, size_t ws_size,
                              hipStream_t stream) {
    const float* x   = (const float*)d_in[0];
    const int*   ei  = (const int*)d_in[1];
    const float* ea  = (const float*)d_in[2];
    const float* Wc1 = (const float*)d_in[4];
    const float* b1  = (const float*)d_in[5];
    const float* Wg  = (const float*)d_in[6];
    const float* bg  = (const float*)d_in[7];
    const float* Wc2 = (const float*)d_in[8];
    const float* b2  = (const float*)d_in[9];
    float* out = (float*)d_out;

    char* ws = (char*)d_ws;
    size_t off = 0;
    auto alloc = [&](size_t bytes) -> void* {
        void* p = ws + off;
        off += (bytes + 255) & ~(size_t)255;
        return p;
    };
    // deg | cnt contiguous -> k_init zeroes both as one 2*NN word range
    float*    deg = (float*)alloc((size_t)NN * 4);      // 31744
    int*      cnt = (int*)alloc((size_t)NN * 4);        // 31744
    int2*     em  = (int2*)alloc((size_t)NN * CAP * 8); // 4.06 MB fixed-cap
    _Float16* xt  = (_Float16*)alloc((size_t)NN * FT * 2);
    _Float16* w2p = (_Float16*)alloc((size_t)16384 * 2);
    _Float16* w1p = (_Float16*)alloc((size_t)8192 * 2);
    _Float16* wgp = (_Float16*)alloc((size_t)1024 * 2);
    (void)ws_size; (void)in_sizes; (void)n_in; (void)out_size;

    k_init<<<162, 256, 0, stream>>>(deg, Wc2, w2p, Wc1, w1p, Wg, wgp);
    k_conv1_fill<<<NN / 4 + EE / 256, 256, 0, stream>>>(x, w1p, b1, wgp, xt,
                                                        ei, ea, deg, cnt, em);
    k_gc2<<<NN / 2, 256, 0, stream>>>(xt, deg, cnt, em, bg, w2p, b2, out);
}

// Round 12
// 101.527 us; speedup vs baseline: 1.0664x; 1.0115x over previous
//
#include <hip/hip_runtime.h>
#include <hip/hip_bf16.h>

#define NN 7936
#define EE 63488
#define CIN 5
#define WW 64
#define KK 8
#define H1C 64
#define H2C 16
#define T1 57            // 64-8+1
#define T2 50            // 57-8+1
#define FT (T1*H2C)      // 912 elems per node for xt (f16)
#define CAP 64           // fixed bucket capacity (P(deg>=64) ~ 1e-35)
#define GSTR 24          // gs row stride in halves (48 B: 16-B aligned rows)

typedef _Float16 half8 __attribute__((ext_vector_type(8)));
typedef _Float16 half4v __attribute__((ext_vector_type(4)));
typedef float f32x4 __attribute__((ext_vector_type(4)));

// ---------------------------------------------------------------------------
// Per-block int64-layout detection: first wave checks high words of the first
// 32 edge indices, ballot, LDS broadcast. ~32 L2-hot ints per block.
__device__ __forceinline__ int block_flag(const int* __restrict__ ei,
                                          int* sflag) {
    if (threadIdx.x < 64) {
        int bad = (threadIdx.x < 32) ? (ei[2 * threadIdx.x + 1] != 0) : 0;
        unsigned long long b = __ballot(bad);
        if (threadIdx.x == 0) *sflag = (b == 0ULL) ? 1 : 0;
    }
    __syncthreads();
    return *sflag;
}

__device__ __forceinline__ int load_row(const int* ei, int f, int e) {
    return f ? ei[2 * e] : ei[e];
}
__device__ __forceinline__ int load_col(const int* ei, int f, int e) {
    return f ? ei[2 * (EE + e)] : ei[EE + e];
}

// ---------------------------------------------------------------------------
// k_init: blocks 0..61 zero deg|cnt (contiguous 2*NN words, 62*256 = 15872
// exactly); blocks 62..161 do weight prep (25600 threads).
// w2p k-order: element e of a B-frag is (ci = g*4 + (e&3), tap = 2*s+(e>>2))
// — taps grouped in halves so the gc2 A-frag is a plain concat of two 8-B
// LDS rows. MFMA sums over k, so any A/B-consistent k-permutation is valid.
__global__ void k_init(float* __restrict__ deg,
                       const float* __restrict__ Wc2, _Float16* __restrict__ w2p,
                       const float* __restrict__ Wc1, _Float16* __restrict__ w1p,
                       const float* __restrict__ Wg, _Float16* __restrict__ wgp) {
    int b = blockIdx.x;
    if (b < 62) {
        // deg and cnt are contiguous in ws: zero both as one word range
        ((int*)deg)[b * 256 + threadIdx.x] = 0;
        return;
    }
    int i = (b - 62) * 256 + threadIdx.x;
    if (i < 16384) {
        // conv2 B-frags: slot=(s*4+lg)*128+nt*16+c, elem e
        int e = i & 7;
        int slot = i >> 3;
        int c  = slot & 15;
        int nt = (slot >> 4) & 7;
        int g  = (slot >> 7) & 3;
        int s  = (slot >> 9) & 3;
        int ci = g * 4 + (e & 3);
        w2p[i] = (_Float16)Wc2[(nt * 16 + c) * 128 + ci * 8 + 2 * s + (e >> 2)];
    } else if (i < 16384 + 8192) {
        // conv1 GEMM1 A-frags with sigma channel permutation
        int j = i - 16384;
        int e = j & 7;
        int m = (j >> 3) & 127;
        int slg = j >> 10;              // 0..7 = s*4+lg
        int ci = (slg >> 2) * 4 + (slg & 3);
        int hi = m >> 6;                // 0 = P, 1 = Q
        int mb = m & 63;
        int mt = mb >> 4, r = mb & 15;
        int sig = hi * 64 + 32 * (mt >> 1) + 8 * (r >> 2) + 4 * (mt & 1) + (r & 3);
        w1p[j] = (ci < CIN) ? (_Float16)Wc1[sig * (CIN * KK) + ci * KK + e]
                            : (_Float16)0.0f;
    } else if (i < 16384 + 8192 + 1024) {
        // conv1 GEMM2 B-frags (Wg)
        int j = i - 16384 - 8192;
        int e = j & 7;
        int f = (j >> 3) & 15;
        int slg = j >> 7;               // 0..7
        int c = (slg >> 2) * 32 + (slg & 3) * 8 + e;
        wgp[j] = (_Float16)Wg[c * H2C + f];
    }
}

// ---------------------------------------------------------------------------
// Merged kernel: blocks [0, NN/4) run conv1 (register-resident, wave = node);
// blocks [NN/4, NN/4+EE/256) run the edge bucket-fill into FIXED-CAPACITY
// buckets em[c*64+pos], storing RAW (src, ew) and accumulating deg[c] here
// (the dinv[src] fold lives in gc2's prefetch path).
__global__ __launch_bounds__(256, 3) void k_conv1_fill(
        const float* __restrict__ x, const _Float16* __restrict__ w1p,
        const float* __restrict__ b1, const _Float16* __restrict__ wgp,
        _Float16* __restrict__ xt,
        const int* __restrict__ ei,
        const float* __restrict__ ew, float* __restrict__ deg,
        int* __restrict__ cnt, int2* __restrict__ em) {
    if (blockIdx.x >= NN / 4) {
        // ---- bucket fill: em[c*64+pos] = (src, ew); deg[c] += ew ----
        __shared__ int sflag;
        int f = block_flag(ei, &sflag);
        int e = (blockIdx.x - NN / 4) * 256 + threadIdx.x;
        if (e < EE) {
            int c = load_col(ei, f, e);
            int r = load_row(ei, f, e);
            float wv = ew[e];
            int pos = atomicAdd(&cnt[c], 1);
            atomicAdd(&deg[c], wv);
            if (pos < CAP)
                em[(c << 6) + pos] = make_int2(r, __float_as_int(wv));
        }
        return;
    }
    // ---- conv1, fully register-resident (zero LDS, zero barriers) ----
    int tid = threadIdx.x;
    int w = tid >> 6, lane = tid & 63;
    int lc = lane & 15, lg = lane >> 4;
    int n = blockIdx.x * 4 + w;
    const float* xg = x + (size_t)n * (CIN * WW);

    const half8* w1v = (const half8*)w1p;
    const half8* wgv = (const half8*)wgp;

    half8 av[2][8];
#pragma unroll
    for (int s = 0; s < 2; ++s)
#pragma unroll
        for (int mt = 0; mt < 8; ++mt)
            av[s][mt] = w1v[(s * 4 + lg) * 128 + mt * 16 + lc];
    half8 bw[2];
#pragma unroll
    for (int s2 = 0; s2 < 2; ++s2) bw[s2] = wgv[(s2 * 4 + lg) * 16 + lc];

    const float* xr0 = xg + (size_t)lg * WW;
    const float* xr1 = xg + (size_t)(4 + lg) * WW;
    bool cok1 = (4 + lg) < CIN;

    f32x4 acc2[4];
#pragma unroll
    for (int mt2 = 0; mt2 < 4; ++mt2) acc2[mt2] = (f32x4)0.0f;

#pragma unroll
    for (int nt = 0; nt < 4; ++nt) {
        int t = nt * 16 + lc;
        half8 bf0, bf1;
#pragma unroll
        for (int e = 0; e < 8; ++e) {
            int tp = t + e;
            bf0[e] = (_Float16)((tp < WW) ? xr0[tp] : 0.0f);
            bf1[e] = (_Float16)((cok1 && tp < WW) ? xr1[tp] : 0.0f);
        }
        f32x4 acc[8];
#pragma unroll
        for (int mt = 0; mt < 8; ++mt) acc[mt] = (f32x4)0.0f;
#pragma unroll
        for (int mt = 0; mt < 8; ++mt)
            acc[mt] = __builtin_amdgcn_mfma_f32_16x16x32_f16(av[0][mt], bf0,
                                                             acc[mt], 0, 0, 0);
#pragma unroll
        for (int mt = 0; mt < 8; ++mt)
            acc[mt] = __builtin_amdgcn_mfma_f32_16x16x32_f16(av[1][mt], bf1,
                                                             acc[mt], 0, 0, 0);
        half4v h4[4];
#pragma unroll
        for (int mtp = 0; mtp < 4; ++mtp) {
            int cb = 32 * (mtp >> 1) + 8 * lg + 4 * (mtp & 1);
            float4 bP = *(const float4*)(b1 + cb);
            float4 bQ = *(const float4*)(b1 + 64 + cb);
            f32x4 P = acc[mtp];
            f32x4 Q = acc[mtp + 4];
            half4v hh;
            hh[0] = (_Float16)((P[0] + bP.x) * (1.0f / (1.0f + __expf(-(Q[0] + bQ.x)))));
            hh[1] = (_Float16)((P[1] + bP.y) * (1.0f / (1.0f + __expf(-(Q[1] + bQ.y)))));
            hh[2] = (_Float16)((P[2] + bP.z) * (1.0f / (1.0f + __expf(-(Q[2] + bQ.z)))));
            hh[3] = (_Float16)((P[3] + bP.w) * (1.0f / (1.0f + __expf(-(Q[3] + bQ.w)))));
            h4[mtp] = hh;
        }
#pragma unroll
        for (int s2 = 0; s2 < 2; ++s2) {
            half8 af = __builtin_shufflevector(h4[2 * s2], h4[2 * s2 + 1],
                                               0, 1, 2, 3, 4, 5, 6, 7);
            acc2[nt] = __builtin_amdgcn_mfma_f32_16x16x32_f16(af, bw[s2],
                                                              acc2[nt], 0, 0, 0);
        }
    }

    _Float16* xtn = xt + (size_t)n * FT;
#pragma unroll
    for (int mt2 = 0; mt2 < 4; ++mt2) {
#pragma unroll
        for (int j = 0; j < 4; ++j) {
            int t = mt2 * 16 + 4 * lg + j;
            if (t < T1) xtn[t * 16 + lc] = (_Float16)acc2[mt2][j];
        }
    }
}

// ---------------------------------------------------------------------------
// Fused gather + conv2, TWO WAVES PER NODE (r9/r10 proven).
// r11 lesson: prefetch DEPTH is not the wall (2-deep ring was neutral) — the
// gather is issue-rate bound. This round is an instruction diet:
//  - UNROLL-BY-2: consume both held rows per iteration, independent acc
//    chains (a[], b[]) merged after the loop; halves loop overhead, doubles
//    FMA ILP. Odd m handled by zero-weight self-row padding.
//  - wv computed at PREFETCH time (rsqrt off the consume path).
//  - UNCONDITIONAL row loads: lanes 50-63 of the h=1 wave over-read <=224 B
//    past the node row (still inside ws: xt is followed by w2p); their
//    garbage never escapes — the gs2 write stays act-masked.
//  - s_setprio(1) around the MFMA cluster (T5: helps independent-wave
//    kernels; gc2 has no inter-wave barrier lockstep during gather).
// gs2 per-NODE [t][f] 48-B rows; one __syncthreads; each wave does 2 of 4
// ntp quadrants; LDS-staged coalesced NONTEMPORAL stores.
__global__ __launch_bounds__(256, 4) void k_gc2(
        const _Float16* __restrict__ xt, const float* __restrict__ deg,
        const int* __restrict__ cnt, const int2* __restrict__ em,
        const float* __restrict__ bg, const _Float16* __restrict__ w2p,
        const float* __restrict__ b2, float* __restrict__ out) {
    __shared__ __align__(16) _Float16 gs2[2][58 * GSTR];   // per node, 2784 B
    __shared__ __align__(16) float gout[4][16 * T2];       // per wave, 3200 B
    int tid = threadIdx.x;
    int w = tid >> 6, lane = tid & 63;
    int lc = lane & 15, lg = lane >> 4;
    int nb = w >> 1, h = w & 1;
    int n = blockIdx.x * 2 + nb;
    bool act = (h == 0) || (lane < 50);
    int idx = (h << 6) + lane;          // half8 index into a node row

    float dc = rsqrtf(deg[n] + 1.0f);
    float a[8], b[8];
    {
        const half8* xs = (const half8*)(xt + (size_t)n * FT);
        half8 u = xs[idx];              // unconditional; masked at gs2 write
#pragma unroll
        for (int j = 0; j < 8; ++j) { a[j] = (float)u[j] * dc; b[j] = 0.0f; }
    }
    int beg = n << 6;
    int m = min(cnt[n], CAP);

    // pad entries: self row (valid address), weight bits = 0 -> wv exactly 0
#define LDEM(K) (((K) < m) ? em[beg + (K)] : make_int2(n, 0))
    int2 rw0 = LDEM(0), rw1 = LDEM(1), rw2 = LDEM(2), rw3 = LDEM(3);
    float wv0 = __int_as_float(rw0.y) * rsqrtf(deg[rw0.x] + 1.0f);
    float wv1 = __int_as_float(rw1.y) * rsqrtf(deg[rw1.x] + 1.0f);
    float wv2 = __int_as_float(rw2.y) * rsqrtf(deg[rw2.x] + 1.0f);
    float wv3 = __int_as_float(rw3.y) * rsqrtf(deg[rw3.x] + 1.0f);
    half8 c0 = ((const half8*)(xt + (size_t)rw0.x * FT))[idx];
    half8 c1 = ((const half8*)(xt + (size_t)rw1.x * FT))[idx];

    for (int i = 0; i < m; i += 2) {
        half8 d0 = c0, d1 = c1;
        float u0 = wv0, u1 = wv1;
        // issue next pair's rows (addresses ready in rw2/rw3)
        c0 = ((const half8*)(xt + (size_t)rw2.x * FT))[idx];
        c1 = ((const half8*)(xt + (size_t)rw3.x * FT))[idx];
        rw0 = rw2; rw1 = rw3; wv0 = wv2; wv1 = wv3;
        rw2 = LDEM(i + 4); rw3 = LDEM(i + 5);
        wv2 = __int_as_float(rw2.y) * rsqrtf(deg[rw2.x] + 1.0f);
        wv3 = __int_as_float(rw3.y) * rsqrtf(deg[rw3.x] + 1.0f);
#pragma unroll
        for (int j = 0; j < 8; ++j) {
            a[j] += (float)d0[j] * u0;      // chain A
            b[j] += (float)d1[j] * u1;      // chain B (independent)
        }
    }
#undef LDEM

    // relu + bias -> gs2[nb][t][f] (48-B rows). Lane owns t = idx>>1,
    // f = (idx&1)*8 .. +8. One b128 write per active lane.
    // Final feature = dc * (x*dc + sum) + bg, relu.
    {
        _Float16* g = gs2[nb];
        int f0 = (lane & 1) * 8;
        int t0 = idx >> 1;
        float4 bgA = *(const float4*)(bg + f0);
        float4 bgB = *(const float4*)(bg + f0 + 4);
        float bv[8] = {bgA.x, bgA.y, bgA.z, bgA.w, bgB.x, bgB.y, bgB.z, bgB.w};
        half8 h0;
#pragma unroll
        for (int j = 0; j < 8; ++j)
            h0[j] = (_Float16)fmaxf((a[j] + b[j]) * dc + bv[j], 0.0f);
        if (act) *(half8*)(g + t0 * GSTR + f0) = h0;
    }
    __syncthreads();   // both halves' gs2 rows visible to both waves

    const _Float16* g = gs2[nb];
    half8 af[4][4];
#pragma unroll
    for (int s = 0; s < 4; ++s)
#pragma unroll
        for (int mt = 0; mt < 4; ++mt) {
            int tb = mt * 16 + lc + 2 * s;
            half4v lo = *(const half4v*)(g + tb * GSTR + lg * 4);
            half4v hh = *(const half4v*)(g + (tb + 1) * GSTR + lg * 4);
            af[s][mt] = __builtin_shufflevector(lo, hh, 0, 1, 2, 3, 4, 5, 6, 7);
        }

    const half8* wsv = (const half8*)w2p;
    float* outn = out + (size_t)n * (H1C * T2);
    float* go = gout[w];
#pragma unroll
    for (int np2 = 0; np2 < 2; ++np2) {
        int ntp = (h << 1) + np2;
        f32x4 aP[4], aQ[4];
#pragma unroll
        for (int mt = 0; mt < 4; ++mt) { aP[mt] = (f32x4)0.0f; aQ[mt] = (f32x4)0.0f; }
        __builtin_amdgcn_s_setprio(1);
#pragma unroll
        for (int s = 0; s < 4; ++s) {
            half8 bP = wsv[(s * 4 + lg) * 128 + ntp * 16 + lc];
            half8 bQ = wsv[(s * 4 + lg) * 128 + (ntp + 4) * 16 + lc];
#pragma unroll
            for (int mt = 0; mt < 4; ++mt) {
                aP[mt] = __builtin_amdgcn_mfma_f32_16x16x32_f16(af[s][mt], bP,
                                                                aP[mt], 0, 0, 0);
                aQ[mt] = __builtin_amdgcn_mfma_f32_16x16x32_f16(af[s][mt], bQ,
                                                                aQ[mt], 0, 0, 0);
            }
        }
        __builtin_amdgcn_s_setprio(0);
        int c = ntp * 16 + lc;
        float bp = b2[c], bq = b2[64 + c];
        // stage [lc][t<50] into wave-private LDS (column-major rows of 50)
#pragma unroll
        for (int mt = 0; mt < 4; ++mt) {
#pragma unroll
            for (int e2 = 0; e2 < 4; ++e2) {
                int t = mt * 16 + lg * 4 + e2;
                if (t < T2) {
                    float vv = (aP[mt][e2] + bp) *
                               (1.0f / (1.0f + __expf(-(aQ[mt][e2] + bq))));
                    go[lc * T2 + t] = vv;
                }
            }
        }
        // coalesced nontemporal writeback: 800 floats = 3x1024B + 128B
        float* dst = outn + ntp * (16 * T2);
#pragma unroll
        for (int i = 0; i < 3; ++i) {
            f32x4 v = *(const f32x4*)(go + i * 256 + lane * 4);
            __builtin_nontemporal_store(v, (f32x4*)(dst + i * 256 + lane * 4));
        }
        if (lane < 8) {
            f32x4 v = *(const f32x4*)(go + 768 + lane * 4);
            __builtin_nontemporal_store(v, (f32x4*)(dst + 768 + lane * 4));
        }
    }
}

// ---------------------------------------------------------------------------
extern "C" void kernel_launch(void* const* d_in, const int* in_sizes, int n_in,
                              void* d_out, int out_size, void* d_ws, size_t ws_size,
                              hipStream_t stream) {
    const float* x   = (const float*)d_in[0];
    const int*   ei  = (const int*)d_in[1];
    const float* ea  = (const float*)d_in[2];
    const float* Wc1 = (const float*)d_in[4];
    const float* b1  = (const float*)d_in[5];
    const float* Wg  = (const float*)d_in[6];
    const float* bg  = (const float*)d_in[7];
    const float* Wc2 = (const float*)d_in[8];
    const float* b2  = (const float*)d_in[9];
    float* out = (float*)d_out;

    char* ws = (char*)d_ws;
    size_t off = 0;
    auto alloc = [&](size_t bytes) -> void* {
        void* p = ws + off;
        off += (bytes + 255) & ~(size_t)255;
        return p;
    };
    // deg | cnt contiguous -> k_init zeroes both as one 2*NN word range
    float*    deg = (float*)alloc((size_t)NN * 4);      // 31744
    int*      cnt = (int*)alloc((size_t)NN * 4);        // 31744
    int2*     em  = (int2*)alloc((size_t)NN * CAP * 8); // 4.06 MB fixed-cap
    _Float16* xt  = (_Float16*)alloc((size_t)NN * FT * 2);
    _Float16* w2p = (_Float16*)alloc((size_t)16384 * 2);
    _Float16* w1p = (_Float16*)alloc((size_t)8192 * 2);
    _Float16* wgp = (_Float16*)alloc((size_t)1024 * 2);
    (void)alloc(4096);                  // read-slack: gc2 over-reads past xt
    (void)ws_size; (void)in_sizes; (void)n_in; (void)out_size;

    k_init<<<162, 256, 0, stream>>>(deg, Wc2, w2p, Wc1, w1p, Wg, wgp);
    k_conv1_fill<<<NN / 4 + EE / 256, 256, 0, stream>>>(x, w1p, b1, wgp, xt,
                                                        ei, ea, deg, cnt, em);
    k_gc2<<<NN / 2, 256, 0, stream>>>(xt, deg, cnt, em, bg, w2p, b2, out);
}